// Round 5
// baseline (366.706 us; speedup 1.0000x reference)
//
#include <hip/hip_runtime.h>
#include <hip/hip_cooperative_groups.h>

namespace cg = cooperative_groups;

// XOR chain = inclusive prefix-XOR along axis 0 of [S=4096, B=8192] int32.
// Round 5: single cooperative kernel, grid.sync() between phases.
//   Phase A: each block XORs its chunk's 32 rows -> ws[chunk][colg] (4 MiB).
//   grid.sync()
//   Phase B: block redundantly XOR-reduces its exclusive prefix from ws
//            (L2/LLC traffic), re-reads its 32 rows (same block = cache-warm),
//            nontemporal-stores the output stream.
// 1024 blocks x 256 thr = exactly 4 blocks/CU at <=128 VGPR -> co-resident.

#define S 4096
#define B4 2048            // uint4 column-groups per row
#define CHUNK 32           // rows per chunk
#define NCHUNK (S / CHUNK) // 128
#define TPB 256
#define NCT (B4 / TPB)     // 8 column tiles
#define NBLK (NCHUNK * NCT)

typedef unsigned int v4u __attribute__((ext_vector_type(4)));

__global__ __launch_bounds__(TPB, 4) void xor_scan_coop(
        const v4u* __restrict__ in, v4u* __restrict__ out,
        v4u* __restrict__ ws) {
    const int ct    = blockIdx.x;                 // 0..NCT-1
    const int chunk = blockIdx.y;                 // 0..NCHUNK-1
    const int colg  = ct * TPB + threadIdx.x;     // 0..B4-1

    // ---- Phase A: chunk total ----
    const v4u* p = in + (size_t)chunk * CHUNK * B4 + colg;
    v4u acc = (v4u){0u, 0u, 0u, 0u};
#pragma unroll 16
    for (int r = 0; r < CHUNK; ++r) {
        acc ^= p[(size_t)r * B4];
    }
    ws[(size_t)chunk * B4 + colg] = acc;

    cg::this_grid().sync();

    // ---- Phase B: exclusive prefix over earlier chunk totals ----
    v4u excl = (v4u){0u, 0u, 0u, 0u};
#pragma unroll 8
    for (int c = 0; c < chunk; ++c) {
        excl ^= ws[(size_t)c * B4 + colg];
    }

    // Local inclusive scan + output write (cache-warm input re-read).
    v4u* q = out + (size_t)chunk * CHUNK * B4 + colg;
#pragma unroll 8
    for (int r = 0; r < CHUNK; ++r) {
        excl ^= p[(size_t)r * B4];
        __builtin_nontemporal_store(excl, &q[(size_t)r * B4]);
    }
}

extern "C" void kernel_launch(void* const* d_in, const int* in_sizes, int n_in,
                              void* d_out, int out_size, void* d_ws, size_t ws_size,
                              hipStream_t stream) {
    const v4u* in = (const v4u*)d_in[0];
    v4u* out = (v4u*)d_out;
    v4u* ws  = (v4u*)d_ws;   // needs NCHUNK * B4 * 16 = 4 MiB

    void* args[] = {(void*)&in, (void*)&out, (void*)&ws};
    dim3 grid(NCT, NCHUNK);   // 8 x 128 = 1024 blocks
    dim3 block(TPB);
    hipLaunchCooperativeKernel((const void*)xor_scan_coop, grid, block,
                               args, 0, stream);
}

// Round 6
// 249.450 us; speedup vs baseline: 1.4701x; 1.4701x over previous
//
#include <hip/hip_runtime.h>

// XOR chain = inclusive prefix-XOR along axis 0 of [S=4096, B=8192] int32.
// Round 6: two bulk-synchronous kernels (coop fusion regressed: sync-bound,
// 42% occ cap, +30us launch). Counters from R5 prove traffic is already at
// the 262 MiB floor (re-read LLC-absorbed) — so the fix is MLP: explicit
// register-batched loads to keep 8-16 HBM requests in flight per wave
// (R5 showed VGPR=32 => compiler was chaining load->xor with ~few in flight).

#define S 4096
#define B4 2048            // uint4 column-groups per row
#define CHUNK 32           // rows per chunk
#define NCHUNK (S / CHUNK) // 128
#define TPB 256
#define NCT (B4 / TPB)     // 8 column tiles

typedef unsigned int v4u __attribute__((ext_vector_type(4)));

// K1: ws[chunk][colg] = XOR of the chunk's 32 rows. 16 loads in flight.
__global__ __launch_bounds__(TPB) void xor_chunk_total(
        const v4u* __restrict__ in, v4u* __restrict__ ws) {
    const int colg  = blockIdx.x * TPB + threadIdx.x;   // 0..B4-1
    const int chunk = blockIdx.y;
    const v4u* p = in + (size_t)chunk * CHUNK * B4 + colg;
    v4u acc = (v4u){0u, 0u, 0u, 0u};
#pragma unroll
    for (int g = 0; g < CHUNK / 16; ++g) {
        v4u v[16];
#pragma unroll
        for (int j = 0; j < 16; ++j)
            v[j] = p[(size_t)(g * 16 + j) * B4];
#pragma unroll
        for (int j = 0; j < 16; ++j)
            acc ^= v[j];
    }
    ws[(size_t)chunk * B4 + colg] = acc;
}

// K3: prefetch first input batch (HBM) -> prefix-reduce ws (L2, 8-deep
// batches) -> double-buffered scan with nontemporal output stores.
__global__ __launch_bounds__(TPB) void xor_scan_out(
        const v4u* __restrict__ in, const v4u* __restrict__ ws,
        v4u* __restrict__ out) {
    const int colg  = blockIdx.x * TPB + threadIdx.x;
    const int chunk = (NCHUNK - 1) - blockIdx.y;  // heavy blocks launch first

    const v4u* p = in  + (size_t)chunk * CHUNK * B4 + colg;
    v4u*       q = out + (size_t)chunk * CHUNK * B4 + colg;

    // Prefetch first 8 input rows — overlaps the L2 prefix reduce below.
    v4u buf[8];
#pragma unroll
    for (int j = 0; j < 8; ++j)
        buf[j] = p[(size_t)j * B4];

    // Exclusive prefix: XOR of ws[0..chunk), 8 independent L2 loads per batch.
    v4u excl = (v4u){0u, 0u, 0u, 0u};
    int c = 0;
    for (; c + 8 <= chunk; c += 8) {
        v4u v[8];
#pragma unroll
        for (int j = 0; j < 8; ++j)
            v[j] = ws[(size_t)(c + j) * B4 + colg];
#pragma unroll
        for (int j = 0; j < 8; ++j)
            excl ^= v[j];
    }
    for (; c < chunk; ++c)
        excl ^= ws[(size_t)c * B4 + colg];

    // Double-buffered local scan: prefetch next 8 rows while consuming 8.
    v4u acc = excl;
#pragma unroll
    for (int g = 0; g < CHUNK / 8; ++g) {
        v4u nxt[8];
        if (g + 1 < CHUNK / 8) {
#pragma unroll
            for (int j = 0; j < 8; ++j)
                nxt[j] = p[(size_t)((g + 1) * 8 + j) * B4];
        }
#pragma unroll
        for (int j = 0; j < 8; ++j) {
            acc ^= buf[j];
            __builtin_nontemporal_store(acc, &q[(size_t)(g * 8 + j) * B4]);
        }
#pragma unroll
        for (int j = 0; j < 8; ++j)
            buf[j] = nxt[j];
    }
}

extern "C" void kernel_launch(void* const* d_in, const int* in_sizes, int n_in,
                              void* d_out, int out_size, void* d_ws, size_t ws_size,
                              hipStream_t stream) {
    const v4u* in = (const v4u*)d_in[0];
    v4u* out = (v4u*)d_out;
    v4u* ws  = (v4u*)d_ws;   // needs NCHUNK * B4 * 16 = 4 MiB

    dim3 grid(NCT, NCHUNK);  // 8 x 128 = 1024 blocks
    xor_chunk_total<<<grid, TPB, 0, stream>>>(in, ws);
    xor_scan_out<<<grid, TPB, 0, stream>>>(in, ws, out);
}

// Round 7
// 244.699 us; speedup vs baseline: 1.4986x; 1.0194x over previous
//
#include <hip/hip_runtime.h>

// XOR chain = inclusive prefix-XOR along axis 0 of [S=4096, B=8192] int32.
// Round 7: single-pass decoupled lookback, fence-free.
// Key facts exploited:
//  - inputs are 0/1 only => a lane's 4-column aggregate packs into a nibble;
//    publish as one dword with in-band marker bit 0x100 (self-validating,
//    no release/acquire fences needed; tables zero-initialized first).
//  - device-scope relaxed atomics publish/poll at the LLC coherence point
//    (no cross-XCD stale-L2 hazard).
//  - ticket assignment: a spinning block only waits on lower tickets, which
//    have provably started => no deadlock.
// Fabric traffic: 128 MiB in-read (once) + 132 MiB out-write + ~20-65 MB
// lookback dwords, vs ~650 MB for the R4/R6 two-kernel structure.

#define S 4096
#define B4 2048            // uint4 column-groups per row
#define CHUNK 32           // rows per chunk (val[32] = 128 VGPRs)
#define NCHUNK (S / CHUNK) // 128
#define TPB 256
#define NCT (B4 / TPB)     // 8 column tiles (chains)
#define NBLK (NCHUNK * NCT)
#define NWORDS (NCHUNK * B4)   // dwords per table (1 MiB)
#define MARK 0x100u

typedef unsigned int v4u __attribute__((ext_vector_type(4)));

__device__ __forceinline__ unsigned pack4(v4u v) {
    return v.x | (v.y << 1) | (v.z << 2) | (v.w << 3);
}

// Zero ticket + agg/inc tables. Plain stores are fine: the dispatch boundary
// release makes them visible to the next kernel's device-scope atomics.
__global__ __launch_bounds__(256) void ws_init(unsigned* __restrict__ w) {
    int i = blockIdx.x * 256 + threadIdx.x;
    const int total = 64 + 2 * NWORDS;
    for (int j = i; j < total; j += 256 * 512) w[j] = 0u;
}

__global__ __launch_bounds__(TPB, 2) void xor_lookback(
        const v4u* __restrict__ in, v4u* __restrict__ out,
        unsigned* __restrict__ ctl) {
    unsigned* agg = ctl + 64;
    unsigned* inc = agg + NWORDS;

    __shared__ unsigned sh_t;
    const int tid = threadIdx.x;
    if (tid == 0) sh_t = atomicAdd(&ctl[0], 1u);
    __syncthreads();
    const unsigned t = sh_t;
    const int ct    = (int)(t & (NCT - 1));
    const int chunk = (int)(t >> 3);
    const int colg  = ct * TPB + tid;

    // Load my 32 rows (all loads in flight), local inclusive prefix in regs.
    const v4u* p = in + (size_t)chunk * CHUNK * B4 + colg;
    v4u val[CHUNK];
#pragma unroll
    for (int r = 0; r < CHUNK; ++r) val[r] = p[(size_t)r * B4];
#pragma unroll
    for (int r = 1; r < CHUNK; ++r) val[r] ^= val[r - 1];

    const unsigned myagg = pack4(val[CHUNK - 1]);
    __hip_atomic_store(&agg[(size_t)chunk * B4 + colg], MARK | myagg,
                       __ATOMIC_RELAXED, __HIP_MEMORY_SCOPE_AGENT);

    // Lookback: per-lane independent walk over predecessor entries.
    unsigned ex = 0u;           // packed exclusive-prefix bits (nibble)
    int k = chunk - 1;
    while (k >= 0) {
        // Fast path: predecessor's inclusive prefix short-circuits the walk.
        unsigned iw = __hip_atomic_load(&inc[(size_t)k * B4 + colg],
                                        __ATOMIC_RELAXED,
                                        __HIP_MEMORY_SCOPE_AGENT);
        if (iw & MARK) { ex ^= (iw & 0xFu); break; }
        // Batch up to 8 aggregate polls (independent loads, one round trip).
        int n = (k + 1 < 8) ? (k + 1) : 8;
        unsigned a[8];
        for (int j = 0; j < n; ++j)
            a[j] = __hip_atomic_load(&agg[(size_t)(k - j) * B4 + colg],
                                     __ATOMIC_RELAXED,
                                     __HIP_MEMORY_SCOPE_AGENT);
        int consumed = 0;
        for (int j = 0; j < n; ++j) {
            if (a[j] & MARK) { ex ^= (a[j] & 0xFu); ++consumed; }
            else break;
        }
        k -= consumed;
        if (consumed == 0) __builtin_amdgcn_s_sleep(1);
    }

    // Publish my inclusive prefix for successors' fast path.
    __hip_atomic_store(&inc[(size_t)chunk * B4 + colg], MARK | (ex ^ myagg),
                       __ATOMIC_RELAXED, __HIP_MEMORY_SCOPE_AGENT);

    // Output: exclusive seed ^ local inclusive values, nontemporal stream.
    v4u seed = (v4u){ex & 1u, (ex >> 1) & 1u, (ex >> 2) & 1u, (ex >> 3) & 1u};
    v4u* q = out + (size_t)chunk * CHUNK * B4 + colg;
#pragma unroll
    for (int r = 0; r < CHUNK; ++r)
        __builtin_nontemporal_store(seed ^ val[r], &q[(size_t)r * B4]);
}

extern "C" void kernel_launch(void* const* d_in, const int* in_sizes, int n_in,
                              void* d_out, int out_size, void* d_ws, size_t ws_size,
                              hipStream_t stream) {
    const v4u* in = (const v4u*)d_in[0];
    v4u* out = (v4u*)d_out;
    unsigned* ctl = (unsigned*)d_ws;   // [0..63] ctl, then agg (1 MiB), inc (1 MiB)

    ws_init<<<512, 256, 0, stream>>>(ctl);
    xor_lookback<<<NBLK, TPB, 0, stream>>>(in, out, ctl);
}